// Round 4
// baseline (517.453 us; speedup 1.0000x reference)
//
#include <hip/hip_runtime.h>
#include <stdint.h>
#include <stddef.h>

typedef int v4i  __attribute__((ext_vector_type(4)));
typedef int v16i __attribute__((ext_vector_type(16)));
typedef _Float16 vh8 __attribute__((ext_vector_type(8)));

#define GELU_A   (-0.2888f)
#define GELU_B   (-1.769f)
#define INV_SQRT2 0.70710678118654752440f

// ---------------------------------------------------------------------------
// Fragment ("flatmm") layout: operand stored as [rows/32][K/32][1024B] where
// byte (lane*16 + j) of frag (rb,kb) = W[rb*32 + (lane&31)][kb*32 + (lane>>5)*16 + j].
// Byte-identical to what the verified LDS kernel fed mfma_i32_32x32x32_i8, so a
// wave's frag load is ONE coalesced global_load_dwordx4 (1KB) -> VGPRs.
// GEMM needs no LDS and no barriers. Round-4 change: prefetch distance 3
// (4-stage register ring, unroll-4 so all indices are static) to cover the
// measured ~500-900cy L3/HBM frag-load latency that distance-1 left exposed.
// ---------------------------------------------------------------------------

// scalar slots: sc[0]=enc(xmin) sc[1]=enc(gmin)  [init 0xFFFFFFFF]
//               sc[2]=enc(xmax) sc[3]=|w1|max bits sc[4]=|w2|max bits sc[5]=enc(gmax) [init 0]

__device__ __forceinline__ unsigned enc_f(float f){
  unsigned u = __float_as_uint(f);
  return (u & 0x80000000u) ? ~u : (u | 0x80000000u);
}
__device__ __forceinline__ float dec_f(unsigned e){
  unsigned u = (e & 0x80000000u) ? (e & 0x7FFFFFFFu) : ~e;
  return __uint_as_float(u);
}

__device__ __forceinline__ float int_gelu_f(float x){
  float t = x * INV_SQRT2;
  float at = fminf(fabsf(t), 1.769f);
  float u = at + GELU_B;                 // in [-1.769, 0]
  float p = GELU_A * (u * u) + 1.0f;
  float L = (t > 0.0f) ? p : ((t < 0.0f) ? -p : 0.0f);
  return x * 0.5f * (1.0f + L);
}

// blocks [0,1024): x min/max; [1024,1152): absmax w1 -> sc[3]; [1152,1280): absmax w2 -> sc[4]
__global__ __launch_bounds__(256) void reduce_stats(
    const float4* __restrict__ x, int nx4,
    const float4* __restrict__ w1, int n14,
    const float4* __restrict__ w2, int n24,
    unsigned* __restrict__ sc)
{
  __shared__ float ra[256], rb[256];
  const int tid = threadIdx.x;
  const int b = blockIdx.x;
  if (b < 1024){
    float lmin = 3.4e38f, lmax = -3.4e38f;
    for (long i = (long)b * 256 + tid; i < nx4; i += 1024L * 256L){
      float4 v = x[i];
      lmin = fminf(lmin, fminf(fminf(v.x, v.y), fminf(v.z, v.w)));
      lmax = fmaxf(lmax, fmaxf(fmaxf(v.x, v.y), fmaxf(v.z, v.w)));
    }
    ra[tid] = lmin; rb[tid] = lmax;
    __syncthreads();
    for (int s = 128; s > 0; s >>= 1){
      if (tid < s){ ra[tid] = fminf(ra[tid], ra[tid + s]); rb[tid] = fmaxf(rb[tid], rb[tid + s]); }
      __syncthreads();
    }
    if (tid == 0){
      atomicMin(&sc[0], enc_f(ra[0]));
      atomicMax(&sc[2], enc_f(rb[0]));
    }
  } else {
    const float4* w; int n4; int slot; int bl;
    if (b < 1152){ w = w1; n4 = n14; slot = 3; bl = b - 1024; }
    else         { w = w2; n4 = n24; slot = 4; bl = b - 1152; }
    float la = 0.0f;
    for (long i = (long)bl * 256 + tid; i < n4; i += 128L * 256L){
      float4 v = w[i];
      la = fmaxf(la, fmaxf(fmaxf(fabsf(v.x), fabsf(v.y)), fmaxf(fabsf(v.z), fabsf(v.w))));
    }
    ra[tid] = la;
    __syncthreads();
    for (int s = 128; s > 0; s >>= 1){
      if (tid < s) ra[tid] = fmaxf(ra[tid], ra[tid + s]);
      __syncthreads();
    }
    if (tid == 0) atomicMax(&sc[slot], __float_as_uint(ra[0]));
  }
}

// quantize 4 floats -> 4 packed uint8 (asym act quant, stored as (q-128))
__device__ __forceinline__ unsigned quant4_act(float4 v, float s, float zp){
  int q0 = (int)fminf(fmaxf(rintf(v.x / s) + zp, 0.0f), 255.0f) - 128;
  int q1 = (int)fminf(fmaxf(rintf(v.y / s) + zp, 0.0f), 255.0f) - 128;
  int q2 = (int)fminf(fmaxf(rintf(v.z / s) + zp, 0.0f), 255.0f) - 128;
  int q3 = (int)fminf(fmaxf(rintf(v.w / s) + zp, 0.0f), 255.0f) - 128;
  return ((unsigned)(q0 & 255)) | ((unsigned)(q1 & 255) << 8) |
         ((unsigned)(q2 & 255) << 16) | ((unsigned)(q3 & 255) << 24);
}

// fused: blocks [0,2048): act-quant x -> qx FRAGMENTED;
//        blocks [2048, 2048+H+D): weight-quant rows -> qw FRAGMENTED (+row sums)
__global__ __launch_bounds__(256) void quant_all(
    const float* __restrict__ x, int8_t* __restrict__ qx, long nchunk,
    const float* __restrict__ w1, const float* __restrict__ w2,
    int8_t* __restrict__ qw1, int8_t* __restrict__ qw2,
    int* __restrict__ rs1, int* __restrict__ rs2,
    const unsigned* __restrict__ sc, int H, int D)
{
  const int tid = threadIdx.x;
  const int b = blockIdx.x;
  if (b < 2048){
    // x: one chunk = 16 consecutive d of one row m -> one 16B frag write
    const float vmin = dec_f(sc[0]);
    const float vmax = dec_f(sc[2]);
    const float s  = fmaxf(vmax - vmin, 1e-8f) / 255.0f;
    const float zp = rintf(-vmin / s);
    const long CPR = (long)(D >> 4);        // chunks per row
    const long KB  = (long)(D >> 5);        // frag K-blocks per row
    for (long i = (long)b * 256 + tid; i < nchunk; i += 2048L * 256L){
      long m = i / CPR; int c = (int)(i - m * CPR);
      const float4* xp = (const float4*)(x + m * (long)D + (long)c * 16);
      uint4 o;
      o.x = quant4_act(xp[0], s, zp);
      o.y = quant4_act(xp[1], s, zp);
      o.z = quant4_act(xp[2], s, zp);
      o.w = quant4_act(xp[3], s, zp);
      size_t off = ((((size_t)(m >> 5)) * KB + (c >> 1)) << 10)
                 + ((size_t)(c & 1) << 9) + ((m & 31) << 4);
      *(uint4*)(qx + off) = o;
    }
  } else {
    __shared__ int red[256];
    const int wb = b - 2048;
    const float* w; int8_t* q; int* rs; int K; int n; float s;
    if (wb < H){ w = w1; q = qw1; rs = rs1; K = D; n = wb;
                 s = fmaxf(__uint_as_float(sc[3]), 1e-8f) / 127.0f; }
    else       { w = w2; q = qw2; rs = rs2; K = H; n = wb - H;
                 s = fmaxf(__uint_as_float(sc[4]), 1e-8f) / 127.0f; }
    int sum = 0;
    const int c = tid;                       // chunk of 16 k (K/16 <= 192 < 256)
    if (c < (K >> 4)){
      const float4* wp = (const float4*)(w + (size_t)n * K + (size_t)c * 16);
      uint4 o; unsigned wds[4];
#pragma unroll
      for (int q4 = 0; q4 < 4; q4++){
        float4 v = wp[q4];
        int qa = (int)fminf(fmaxf(rintf(v.x / s), -128.0f), 127.0f);
        int qb = (int)fminf(fmaxf(rintf(v.y / s), -128.0f), 127.0f);
        int qc = (int)fminf(fmaxf(rintf(v.z / s), -128.0f), 127.0f);
        int qd = (int)fminf(fmaxf(rintf(v.w / s), -128.0f), 127.0f);
        sum += qa + qb + qc + qd;
        wds[q4] = ((unsigned)(qa & 255)) | ((unsigned)(qb & 255) << 8) |
                  ((unsigned)(qc & 255) << 16) | ((unsigned)(qd & 255) << 24);
      }
      o.x = wds[0]; o.y = wds[1]; o.z = wds[2]; o.w = wds[3];
      size_t off = ((((size_t)(n >> 5)) * (K >> 5) + (c >> 1)) << 10)
                 + ((size_t)(c & 1) << 9) + ((n & 31) << 4);
      *(uint4*)(q + off) = o;
    }
    red[tid] = sum;
    __syncthreads();
    for (int st = 128; st > 0; st >>= 1){
      if (tid < st) red[tid] += red[tid + st];
      __syncthreads();
    }
    if (tid == 0) rs[n] = red[0];
  }
}

// g (fragmented fp16, written by GEMM1) -> qg (fragmented int8, (q-128)).
// Pure 2:1 recode: out-chunk i (16B) = quantize(gf bytes [32i, 32i+32)).
__global__ __launch_bounds__(256) void quant_g(
    const vh8* __restrict__ gf, uint4* __restrict__ qg, long nchunk,
    const unsigned* __restrict__ sc)
{
  const float gmin = dec_f(sc[1]), gmax = dec_f(sc[5]);
  const float qs  = fmaxf(gmax - gmin, 1e-8f) / 255.0f;
  const float qzp = rintf(-gmin / qs);
  const long stride = (long)gridDim.x * blockDim.x;
  for (long i = (long)blockIdx.x * blockDim.x + threadIdx.x; i < nchunk; i += stride){
    vh8 v0 = gf[2 * i], v1 = gf[2 * i + 1];
    unsigned wds[4] = {0u, 0u, 0u, 0u};
#pragma unroll
    for (int j = 0; j < 8; j++){
      int q = (int)fminf(fmaxf(rintf((float)v0[j] / qs) + qzp, 0.0f), 255.0f) - 128;
      wds[j >> 2] |= ((unsigned)(q & 255)) << (8 * (j & 3));
    }
#pragma unroll
    for (int j = 0; j < 8; j++){
      int q = (int)fminf(fmaxf(rintf((float)v1[j] / qs) + qzp, 0.0f), 255.0f) - 128;
      wds[2 + (j >> 2)] |= ((unsigned)(q & 255)) << (8 * (j & 3));
    }
    uint4 o; o.x = wds[0]; o.y = wds[1]; o.z = wds[2]; o.w = wds[3];
    qg[i] = o;
  }
}

// Flat (LDS-free, barrier-free) int8 GEMM on pre-fragmented operands.
// MODE 0: h->gelu-> g min/max atomics only (no store)            [fallback pass A]
// MODE 3: h->gelu-> store g fp16 FRAGMENTED + g min/max atomics  [main pass A]
// MODE 2: h->gelu-> quantize -> store int8 FRAGMENTED (q-128)    [fallback pass B]
// MODE 1: h + bias -> store fp32 out LINEAR                      [GEMM2]
//
// 128x128 tile, 4 waves (2Mx2N) of 64x64, mfma_i32_32x32x32_i8, K-step 32.
// Register ring of 4 frag stages, prefetch distance 3, loop unrolled x4 so all
// ring indices are compile-time constants (runtime-indexed vectors -> scratch).
template<int MODE>
__global__ __launch_bounds__(256, 4) void gemm_i8f(
    const int8_t* __restrict__ Af, const int8_t* __restrict__ Bf,
    const int* __restrict__ rowsum, const float* __restrict__ bias,
    void* __restrict__ Cout, int M, int N, int K,
    unsigned* __restrict__ sc)
{
  const int tid  = threadIdx.x;
  const int lane = tid & 63;
  const int wave = tid >> 6;
  const int l31  = lane & 31;
  const int kh   = lane >> 5;
  const int n0   = blockIdx.x * 128;
  const int m0   = blockIdx.y * 128;
  const int wm   = (wave & 1) * 64;
  const int wn   = (wave >> 1) * 64;
  const int NKB  = K >> 5;               // k-32 blocks (24 or 96; multiple of 4)
  const int MBmax = (M >> 5) - 1;

  const int8_t* apt[2]; const int8_t* bpt[2];
#pragma unroll
  for (int mi = 0; mi < 2; mi++){
    int rb = (m0 + wm + mi * 32) >> 5; if (rb > MBmax) rb = MBmax;  // clamp (dup frag, never stored)
    apt[mi] = Af + ((size_t)rb * NKB) * 1024 + lane * 16;
  }
#pragma unroll
  for (int nj = 0; nj < 2; nj++){
    int cb = (n0 + wn + nj * 32) >> 5;
    bpt[nj] = Bf + ((size_t)cb * NKB) * 1024 + lane * 16;
  }

  v16i acc[2][2] = {};
  v4i a[4][2], b[4][2];                  // 4-stage ring (static indices only)

#define LOADS(S, KB) do{ const size_t _o = ((size_t)(KB)) << 10;              \
    a[S][0] = *(const v4i*)(apt[0] + _o); a[S][1] = *(const v4i*)(apt[1] + _o);\
    b[S][0] = *(const v4i*)(bpt[0] + _o); b[S][1] = *(const v4i*)(bpt[1] + _o);\
  }while(0)
#define MM(S) do{                                                              \
    acc[0][0] = __builtin_amdgcn_mfma_i32_32x32x32_i8(a[S][0], b[S][0], acc[0][0], 0, 0, 0); \
    acc[1][0] = __builtin_amdgcn_mfma_i32_32x32x32_i8(a[S][1], b[S][0], acc[1][0], 0, 0, 0); \
    acc[0][1] = __builtin_amdgcn_mfma_i32_32x32x32_i8(a[S][0], b[S][1], acc[0][1], 0, 0, 0); \
    acc[1][1] = __builtin_amdgcn_mfma_i32_32x32x32_i8(a[S][1], b[S][1], acc[1][1], 0, 0, 0); \
  }while(0)

  LOADS(0, 0); LOADS(1, 1); LOADS(2, 2);   // preload stages 0..2

  for (int kb = 0; kb < NKB; kb += 4){
    if (kb + 3 < NKB) LOADS(3, kb + 3);
    __builtin_amdgcn_sched_barrier(0);
    MM(0);
    if (kb + 4 < NKB) LOADS(0, kb + 4);
    __builtin_amdgcn_sched_barrier(0);
    MM(1);
    if (kb + 5 < NKB) LOADS(1, kb + 5);
    __builtin_amdgcn_sched_barrier(0);
    MM(2);
    if (kb + 6 < NKB) LOADS(2, kb + 6);
    __builtin_amdgcn_sched_barrier(0);
    MM(3);
  }
#undef LOADS
#undef MM

  // epilogue scalars
  float s_h, off_h;
  if constexpr (MODE == 1){
    float gmin = dec_f(sc[1]), gmax = dec_f(sc[5]);
    float sg = fmaxf(gmax - gmin, 1e-8f) / 255.0f;
    float zp = rintf(-gmin / sg);
    float sw = fmaxf(__uint_as_float(sc[4]), 1e-8f) / 127.0f;
    s_h = sg * sw; off_h = 128.0f - zp;
  } else {
    float xmin = dec_f(sc[0]), xmax = dec_f(sc[2]);
    float sx = fmaxf(xmax - xmin, 1e-8f) / 255.0f;
    float zp = rintf(-xmin / sx);
    float sw = fmaxf(__uint_as_float(sc[3]), 1e-8f) / 127.0f;
    s_h = sx * sw; off_h = 128.0f - zp;
  }
  float qs = 1.0f, qzp = 0.0f;
  if constexpr (MODE == 2){
    float gmin = dec_f(sc[1]), gmax = dec_f(sc[5]);
    qs = fmaxf(gmax - gmin, 1e-8f) / 255.0f;
    qzp = rintf(-gmin / qs);
  }

  // C/D 32x32 layout: col = lane&31, row = (reg&3) + 8*(reg>>2) + 4*(lane>>5)
  float lmin = 3.4e38f, lmax = -3.4e38f;
#pragma unroll
  for (int nj = 0; nj < 2; nj++){
    const int n = n0 + wn + nj * 32 + l31;
    const float rsv = off_h * (float)rowsum[n];
    const float bv = bias[n];
#pragma unroll
    for (int mi = 0; mi < 2; mi++){
      const int mbase = m0 + wm + mi * 32 + 4 * kh;
#pragma unroll
      for (int r = 0; r < 16; r++){
        const int m = mbase + (r & 3) + 8 * (r >> 2);
        if (m < M){
          float h = s_h * ((float)acc[mi][nj][r] + rsv) + bv;
          if constexpr (MODE == 0){
            float gv = int_gelu_f(h);
            lmin = fminf(lmin, gv); lmax = fmaxf(lmax, gv);
          } else if constexpr (MODE == 3){
            float gv = int_gelu_f(h);
            lmin = fminf(lmin, gv); lmax = fmaxf(lmax, gv);
            size_t hidx = ((((size_t)(m >> 5)) * (N >> 5) + (n >> 5)) << 10)
                        + ((size_t)((n >> 4) & 1) << 9) + ((m & 31) << 4) + (n & 15);
            ((_Float16*)Cout)[hidx] = (_Float16)gv;
          } else if constexpr (MODE == 2){
            float gv = int_gelu_f(h);
            float qf = fminf(fmaxf(rintf(gv / qs) + qzp, 0.0f), 255.0f);
            size_t bidx = ((((size_t)(m >> 5)) * (N >> 5) + (n >> 5)) << 10)
                        + ((size_t)((n >> 4) & 1) << 9) + ((m & 31) << 4) + (n & 15);
            ((int8_t*)Cout)[bidx] = (int8_t)((int)qf - 128);
          } else {
            ((float*)Cout)[(size_t)m * N + n] = h;
          }
        }
      }
    }
  }

  if constexpr (MODE == 0 || MODE == 3){
    __shared__ float redA[256], redB[256];
    redA[tid] = lmin; redB[tid] = lmax;
    __syncthreads();
    for (int st = 128; st > 0; st >>= 1){
      if (tid < st){
        redA[tid] = fminf(redA[tid], redA[tid + st]);
        redB[tid] = fmaxf(redB[tid], redB[tid + st]);
      }
      __syncthreads();
    }
    if (tid == 0){
      atomicMin(&sc[1], enc_f(redA[0]));
      atomicMax(&sc[5], enc_f(redB[0]));
    }
  }
}

extern "C" void kernel_launch(void* const* d_in, const int* in_sizes, int n_in,
                              void* d_out, int out_size, void* d_ws, size_t ws_size,
                              hipStream_t stream)
{
  const float* x  = (const float*)d_in[0];
  const float* w1 = (const float*)d_in[1];
  const float* b1 = (const float*)d_in[2];
  const float* w2 = (const float*)d_in[3];
  const float* b2 = (const float*)d_in[4];
  float* out = (float*)d_out;

  const int H = in_sizes[2];            // 3072
  const int D = in_sizes[4];            // 768
  const int M = in_sizes[0] / D;        // 12608 (multiple of 32)

  char* ws = (char*)d_ws;
  unsigned* sc = (unsigned*)ws;
  size_t off = 256;
  int8_t* qx  = (int8_t*)(ws + off); off += (size_t)M * D;   // 9.68 MB  (fragmented)
  int8_t* qw1 = (int8_t*)(ws + off); off += (size_t)H * D;   // 2.36 MB  (fragmented)
  int8_t* qw2 = (int8_t*)(ws + off); off += (size_t)D * H;   // 2.36 MB  (fragmented)
  int* rs1 = (int*)(ws + off); off += (size_t)H * 4;
  int* rs2 = (int*)(ws + off); off += 4096;
  int8_t* qg  = (int8_t*)(ws + off); off += (size_t)M * H;   // 38.7 MB  (fragmented)
  _Float16* g16 = (_Float16*)(ws + off);                      // 77.5 MB  (fragmented fp16)
  const size_t need_big = off + (size_t)M * H * 2;
  (void)n_in; (void)out_size;

  // scalar init: slots 0,1 = 0xFFFFFFFF (encoded +inf for min); 2..5 = 0
  hipMemsetAsync(sc, 0xFF, 8, stream);
  hipMemsetAsync(sc + 2, 0x00, 16, stream);

  reduce_stats<<<dim3(1280), dim3(256), 0, stream>>>(
      (const float4*)x, M * D / 4,
      (const float4*)w1, H * D / 4,
      (const float4*)w2, D * H / 4, sc);

  quant_all<<<dim3(2048 + H + D), dim3(256), 0, stream>>>(
      x, qx, (long)M * D / 16,
      w1, w2, qw1, qw2, rs1, rs2, sc, H, D);

  const dim3 g1(H / 128, (M + 127) / 128), g2(D / 128, (M + 127) / 128), blk(256);

  if (ws_size >= need_big){
    // GEMM1 (single pass): g stats + store g fp16 (fragmented)
    gemm_i8f<3><<<g1, blk, 0, stream>>>(qx, qw1, rs1, b1, g16, M, H, D, sc);
    // recode g (frag fp16) -> qg (frag int8)
    quant_g<<<dim3(2048), dim3(256), 0, stream>>>(
        (const vh8*)g16, (uint4*)qg, (long)M * H / 16, sc);
  } else {
    // fallback: exact 2-pass GEMM1 (stats, then quantize)
    gemm_i8f<0><<<g1, blk, 0, stream>>>(qx, qw1, rs1, b1, nullptr, M, H, D, sc);
    gemm_i8f<2><<<g1, blk, 0, stream>>>(qx, qw1, rs1, b1, qg, M, H, D, sc);
  }

  // GEMM2: out = qg @ qw2^T + b2
  gemm_i8f<1><<<g2, blk, 0, stream>>>(qg, qw2, rs2, b2, out, M, D, H, sc);
}

// Round 5
// 326.157 us; speedup vs baseline: 1.5865x; 1.5865x over previous
//
#include <hip/hip_runtime.h>
#include <stdint.h>
#include <stddef.h>

typedef int v4i  __attribute__((ext_vector_type(4)));
typedef int v16i __attribute__((ext_vector_type(16)));
typedef _Float16 vh8 __attribute__((ext_vector_type(8)));

#define GELU_A   (-0.2888f)
#define GELU_B   (-1.769f)
#define INV_SQRT2 0.70710678118654752440f

// ---------------------------------------------------------------------------
// Fragment ("flatmm") layout: operand stored as [rows/32][K/32][1024B] where
// byte (lane*16 + j) of frag (rb,kb) = W[rb*32 + (lane&31)][kb*32 + (lane>>5)*16 + j].
// Wave frag load = ONE coalesced global_load_dwordx4 (1KB) -> VGPRs; no LDS,
// no barriers. Round-5: (a) __launch_bounds__(256,3) so the 4-stage ring
// (acc 64 + ring 64 + misc ~ 150 regs, unified VGPR/AGPR file) does NOT spill
// (round-4's (256,4) cap=128 spilled -> 570MB scratch traffic); (b) bijective
// chunked XCD swizzle so blocks sharing an A panel land on one XCD's L2.
// ---------------------------------------------------------------------------

// scalar slots: sc[0]=enc(xmin) sc[1]=enc(gmin)  [init 0xFFFFFFFF]
//               sc[2]=enc(xmax) sc[3]=|w1|max bits sc[4]=|w2|max bits sc[5]=enc(gmax) [init 0]

__device__ __forceinline__ unsigned enc_f(float f){
  unsigned u = __float_as_uint(f);
  return (u & 0x80000000u) ? ~u : (u | 0x80000000u);
}
__device__ __forceinline__ float dec_f(unsigned e){
  unsigned u = (e & 0x80000000u) ? (e & 0x7FFFFFFFu) : ~e;
  return __uint_as_float(u);
}

__device__ __forceinline__ float int_gelu_f(float x){
  float t = x * INV_SQRT2;
  float at = fminf(fabsf(t), 1.769f);
  float u = at + GELU_B;                 // in [-1.769, 0]
  float p = GELU_A * (u * u) + 1.0f;
  float L = (t > 0.0f) ? p : ((t < 0.0f) ? -p : 0.0f);
  return x * 0.5f * (1.0f + L);
}

// blocks [0,1024): x min/max; [1024,1152): absmax w1 -> sc[3]; [1152,1280): absmax w2 -> sc[4]
__global__ __launch_bounds__(256) void reduce_stats(
    const float4* __restrict__ x, int nx4,
    const float4* __restrict__ w1, int n14,
    const float4* __restrict__ w2, int n24,
    unsigned* __restrict__ sc)
{
  __shared__ float ra[256], rb[256];
  const int tid = threadIdx.x;
  const int b = blockIdx.x;
  if (b < 1024){
    float lmin = 3.4e38f, lmax = -3.4e38f;
    for (long i = (long)b * 256 + tid; i < nx4; i += 1024L * 256L){
      float4 v = x[i];
      lmin = fminf(lmin, fminf(fminf(v.x, v.y), fminf(v.z, v.w)));
      lmax = fmaxf(lmax, fmaxf(fmaxf(v.x, v.y), fmaxf(v.z, v.w)));
    }
    ra[tid] = lmin; rb[tid] = lmax;
    __syncthreads();
    for (int s = 128; s > 0; s >>= 1){
      if (tid < s){ ra[tid] = fminf(ra[tid], ra[tid + s]); rb[tid] = fmaxf(rb[tid], rb[tid + s]); }
      __syncthreads();
    }
    if (tid == 0){
      atomicMin(&sc[0], enc_f(ra[0]));
      atomicMax(&sc[2], enc_f(rb[0]));
    }
  } else {
    const float4* w; int n4; int slot; int bl;
    if (b < 1152){ w = w1; n4 = n14; slot = 3; bl = b - 1024; }
    else         { w = w2; n4 = n24; slot = 4; bl = b - 1152; }
    float la = 0.0f;
    for (long i = (long)bl * 256 + tid; i < n4; i += 128L * 256L){
      float4 v = w[i];
      la = fmaxf(la, fmaxf(fmaxf(fabsf(v.x), fabsf(v.y)), fmaxf(fabsf(v.z), fabsf(v.w))));
    }
    ra[tid] = la;
    __syncthreads();
    for (int s = 128; s > 0; s >>= 1){
      if (tid < s) ra[tid] = fmaxf(ra[tid], ra[tid + s]);
      __syncthreads();
    }
    if (tid == 0) atomicMax(&sc[slot], __float_as_uint(ra[0]));
  }
}

// quantize 4 floats -> 4 packed uint8 (asym act quant, stored as (q-128))
__device__ __forceinline__ unsigned quant4_act(float4 v, float s, float zp){
  int q0 = (int)fminf(fmaxf(rintf(v.x / s) + zp, 0.0f), 255.0f) - 128;
  int q1 = (int)fminf(fmaxf(rintf(v.y / s) + zp, 0.0f), 255.0f) - 128;
  int q2 = (int)fminf(fmaxf(rintf(v.z / s) + zp, 0.0f), 255.0f) - 128;
  int q3 = (int)fminf(fmaxf(rintf(v.w / s) + zp, 0.0f), 255.0f) - 128;
  return ((unsigned)(q0 & 255)) | ((unsigned)(q1 & 255) << 8) |
         ((unsigned)(q2 & 255) << 16) | ((unsigned)(q3 & 255) << 24);
}

// fused: blocks [0,2048): act-quant x -> qx FRAGMENTED;
//        blocks [2048, 2048+H+D): weight-quant rows -> qw FRAGMENTED (+row sums)
__global__ __launch_bounds__(256) void quant_all(
    const float* __restrict__ x, int8_t* __restrict__ qx, long nchunk,
    const float* __restrict__ w1, const float* __restrict__ w2,
    int8_t* __restrict__ qw1, int8_t* __restrict__ qw2,
    int* __restrict__ rs1, int* __restrict__ rs2,
    const unsigned* __restrict__ sc, int H, int D)
{
  const int tid = threadIdx.x;
  const int b = blockIdx.x;
  if (b < 2048){
    // x: one chunk = 16 consecutive d of one row m -> one 16B frag write
    const float vmin = dec_f(sc[0]);
    const float vmax = dec_f(sc[2]);
    const float s  = fmaxf(vmax - vmin, 1e-8f) / 255.0f;
    const float zp = rintf(-vmin / s);
    const long CPR = (long)(D >> 4);        // chunks per row
    const long KB  = (long)(D >> 5);        // frag K-blocks per row
    for (long i = (long)b * 256 + tid; i < nchunk; i += 2048L * 256L){
      long m = i / CPR; int c = (int)(i - m * CPR);
      const float4* xp = (const float4*)(x + m * (long)D + (long)c * 16);
      uint4 o;
      o.x = quant4_act(xp[0], s, zp);
      o.y = quant4_act(xp[1], s, zp);
      o.z = quant4_act(xp[2], s, zp);
      o.w = quant4_act(xp[3], s, zp);
      size_t off = ((((size_t)(m >> 5)) * KB + (c >> 1)) << 10)
                 + ((size_t)(c & 1) << 9) + ((m & 31) << 4);
      *(uint4*)(qx + off) = o;
    }
  } else {
    __shared__ int red[256];
    const int wb = b - 2048;
    const float* w; int8_t* q; int* rs; int K; int n; float s;
    if (wb < H){ w = w1; q = qw1; rs = rs1; K = D; n = wb;
                 s = fmaxf(__uint_as_float(sc[3]), 1e-8f) / 127.0f; }
    else       { w = w2; q = qw2; rs = rs2; K = H; n = wb - H;
                 s = fmaxf(__uint_as_float(sc[4]), 1e-8f) / 127.0f; }
    int sum = 0;
    const int c = tid;                       // chunk of 16 k (K/16 <= 192 < 256)
    if (c < (K >> 4)){
      const float4* wp = (const float4*)(w + (size_t)n * K + (size_t)c * 16);
      uint4 o; unsigned wds[4];
#pragma unroll
      for (int q4 = 0; q4 < 4; q4++){
        float4 v = wp[q4];
        int qa = (int)fminf(fmaxf(rintf(v.x / s), -128.0f), 127.0f);
        int qb = (int)fminf(fmaxf(rintf(v.y / s), -128.0f), 127.0f);
        int qc = (int)fminf(fmaxf(rintf(v.z / s), -128.0f), 127.0f);
        int qd = (int)fminf(fmaxf(rintf(v.w / s), -128.0f), 127.0f);
        sum += qa + qb + qc + qd;
        wds[q4] = ((unsigned)(qa & 255)) | ((unsigned)(qb & 255) << 8) |
                  ((unsigned)(qc & 255) << 16) | ((unsigned)(qd & 255) << 24);
      }
      o.x = wds[0]; o.y = wds[1]; o.z = wds[2]; o.w = wds[3];
      size_t off = ((((size_t)(n >> 5)) * (K >> 5) + (c >> 1)) << 10)
                 + ((size_t)(c & 1) << 9) + ((n & 31) << 4);
      *(uint4*)(q + off) = o;
    }
    red[tid] = sum;
    __syncthreads();
    for (int st = 128; st > 0; st >>= 1){
      if (tid < st) red[tid] += red[tid + st];
      __syncthreads();
    }
    if (tid == 0) rs[n] = red[0];
  }
}

// g (fragmented fp16, written by GEMM1) -> qg (fragmented int8, (q-128)).
// Pure 2:1 recode: out-chunk i (16B) = quantize(gf bytes [32i, 32i+32)).
__global__ __launch_bounds__(256) void quant_g(
    const vh8* __restrict__ gf, uint4* __restrict__ qg, long nchunk,
    const unsigned* __restrict__ sc)
{
  const float gmin = dec_f(sc[1]), gmax = dec_f(sc[5]);
  const float qs  = fmaxf(gmax - gmin, 1e-8f) / 255.0f;
  const float qzp = rintf(-gmin / qs);
  const long stride = (long)gridDim.x * blockDim.x;
  for (long i = (long)blockIdx.x * blockDim.x + threadIdx.x; i < nchunk; i += stride){
    vh8 v0 = gf[2 * i], v1 = gf[2 * i + 1];
    unsigned wds[4] = {0u, 0u, 0u, 0u};
#pragma unroll
    for (int j = 0; j < 8; j++){
      int q = (int)fminf(fmaxf(rintf((float)v0[j] / qs) + qzp, 0.0f), 255.0f) - 128;
      wds[j >> 2] |= ((unsigned)(q & 255)) << (8 * (j & 3));
    }
#pragma unroll
    for (int j = 0; j < 8; j++){
      int q = (int)fminf(fmaxf(rintf((float)v1[j] / qs) + qzp, 0.0f), 255.0f) - 128;
      wds[2 + (j >> 2)] |= ((unsigned)(q & 255)) << (8 * (j & 3));
    }
    uint4 o; o.x = wds[0]; o.y = wds[1]; o.z = wds[2]; o.w = wds[3];
    qg[i] = o;
  }
}

// Flat (LDS-free, barrier-free) int8 GEMM on pre-fragmented operands.
// MODE 0: h->gelu-> g min/max atomics only (no store)            [fallback pass A]
// MODE 3: h->gelu-> store g fp16 FRAGMENTED + g min/max atomics  [main pass A]
// MODE 2: h->gelu-> quantize -> store int8 FRAGMENTED (q-128)    [fallback pass B]
// MODE 1: h + bias -> store fp32 out LINEAR                      [GEMM2]
//
// 128x128 tile, 4 waves (2Mx2N) of 64x64, mfma_i32_32x32x32_i8, K-step 32.
// 4-stage register ring (prefetch distance 3), unroll-4 (static indices).
// __launch_bounds__(256,3): reg cap ~170 so acc(64)+ring(64)+misc fits, NO spill.
template<int MODE>
__global__ __launch_bounds__(256, 3) void gemm_i8f(
    const int8_t* __restrict__ Af, const int8_t* __restrict__ Bf,
    const int* __restrict__ rowsum, const float* __restrict__ bias,
    void* __restrict__ Cout, int M, int N, int K,
    unsigned* __restrict__ sc)
{
  const int tid  = threadIdx.x;
  const int lane = tid & 63;
  const int wave = tid >> 6;
  const int l31  = lane & 31;
  const int kh   = lane >> 5;

  // bijective chunked XCD swizzle (m204): XCD c = orig%8 gets the contiguous
  // work-id chunk; blocks sharing an A panel (consecutive work ids) co-locate.
  const int nwg  = gridDim.x * gridDim.y;
  const int orig = blockIdx.y * gridDim.x + blockIdx.x;
  const int xcd  = orig & 7, idx = orig >> 3;
  const int q8   = nwg >> 3, r8 = nwg & 7;
  const int wgid = (xcd < r8 ? xcd * (q8 + 1) : r8 * (q8 + 1) + (xcd - r8) * q8) + idx;
  const int bx   = wgid % gridDim.x;
  const int by   = wgid / gridDim.x;

  const int n0   = bx * 128;
  const int m0   = by * 128;
  const int wm   = (wave & 1) * 64;
  const int wn   = (wave >> 1) * 64;
  const int NKB  = K >> 5;               // k-32 blocks (24 or 96; multiple of 4)
  const int MBmax = (M >> 5) - 1;

  const int8_t* apt[2]; const int8_t* bpt[2];
#pragma unroll
  for (int mi = 0; mi < 2; mi++){
    int rb = (m0 + wm + mi * 32) >> 5; if (rb > MBmax) rb = MBmax;  // clamp (dup frag, never stored)
    apt[mi] = Af + ((size_t)rb * NKB) * 1024 + lane * 16;
  }
#pragma unroll
  for (int nj = 0; nj < 2; nj++){
    int cb = (n0 + wn + nj * 32) >> 5;
    bpt[nj] = Bf + ((size_t)cb * NKB) * 1024 + lane * 16;
  }

  v16i acc[2][2] = {};
  v4i a[4][2], b[4][2];                  // 4-stage ring (static indices only)

#define LOADS(S, KB) do{ const size_t _o = ((size_t)(KB)) << 10;              \
    a[S][0] = *(const v4i*)(apt[0] + _o); a[S][1] = *(const v4i*)(apt[1] + _o);\
    b[S][0] = *(const v4i*)(bpt[0] + _o); b[S][1] = *(const v4i*)(bpt[1] + _o);\
  }while(0)
#define MM(S) do{                                                              \
    acc[0][0] = __builtin_amdgcn_mfma_i32_32x32x32_i8(a[S][0], b[S][0], acc[0][0], 0, 0, 0); \
    acc[1][0] = __builtin_amdgcn_mfma_i32_32x32x32_i8(a[S][1], b[S][0], acc[1][0], 0, 0, 0); \
    acc[0][1] = __builtin_amdgcn_mfma_i32_32x32x32_i8(a[S][0], b[S][1], acc[0][1], 0, 0, 0); \
    acc[1][1] = __builtin_amdgcn_mfma_i32_32x32x32_i8(a[S][1], b[S][1], acc[1][1], 0, 0, 0); \
  }while(0)

  LOADS(0, 0); LOADS(1, 1); LOADS(2, 2);   // preload stages 0..2

  for (int kb = 0; kb < NKB; kb += 4){
    if (kb + 3 < NKB) LOADS(3, kb + 3);
    __builtin_amdgcn_sched_barrier(0);
    MM(0);
    if (kb + 4 < NKB) LOADS(0, kb + 4);
    __builtin_amdgcn_sched_barrier(0);
    MM(1);
    if (kb + 5 < NKB) LOADS(1, kb + 5);
    __builtin_amdgcn_sched_barrier(0);
    MM(2);
    if (kb + 6 < NKB) LOADS(2, kb + 6);
    __builtin_amdgcn_sched_barrier(0);
    MM(3);
  }
#undef LOADS
#undef MM

  // epilogue scalars
  float s_h, off_h;
  if constexpr (MODE == 1){
    float gmin = dec_f(sc[1]), gmax = dec_f(sc[5]);
    float sg = fmaxf(gmax - gmin, 1e-8f) / 255.0f;
    float zp = rintf(-gmin / sg);
    float sw = fmaxf(__uint_as_float(sc[4]), 1e-8f) / 127.0f;
    s_h = sg * sw; off_h = 128.0f - zp;
  } else {
    float xmin = dec_f(sc[0]), xmax = dec_f(sc[2]);
    float sx = fmaxf(xmax - xmin, 1e-8f) / 255.0f;
    float zp = rintf(-xmin / sx);
    float sw = fmaxf(__uint_as_float(sc[3]), 1e-8f) / 127.0f;
    s_h = sx * sw; off_h = 128.0f - zp;
  }
  float qs = 1.0f, qzp = 0.0f;
  if constexpr (MODE == 2){
    float gmin = dec_f(sc[1]), gmax = dec_f(sc[5]);
    qs = fmaxf(gmax - gmin, 1e-8f) / 255.0f;
    qzp = rintf(-gmin / qs);
  }

  // C/D 32x32 layout: col = lane&31, row = (reg&3) + 8*(reg>>2) + 4*(lane>>5)
  float lmin = 3.4e38f, lmax = -3.4e38f;
#pragma unroll
  for (int nj = 0; nj < 2; nj++){
    const int n = n0 + wn + nj * 32 + l31;
    const float rsv = off_h * (float)rowsum[n];
    const float bv = bias[n];
#pragma unroll
    for (int mi = 0; mi < 2; mi++){
      const int mbase = m0 + wm + mi * 32 + 4 * kh;
#pragma unroll
      for (int r = 0; r < 16; r++){
        const int m = mbase + (r & 3) + 8 * (r >> 2);
        if (m < M){
          float h = s_h * ((float)acc[mi][nj][r] + rsv) + bv;
          if constexpr (MODE == 0){
            float gv = int_gelu_f(h);
            lmin = fminf(lmin, gv); lmax = fmaxf(lmax, gv);
          } else if constexpr (MODE == 3){
            float gv = int_gelu_f(h);
            lmin = fminf(lmin, gv); lmax = fmaxf(lmax, gv);
            size_t hidx = ((((size_t)(m >> 5)) * (N >> 5) + (n >> 5)) << 10)
                        + ((size_t)((n >> 4) & 1) << 9) + ((m & 31) << 4) + (n & 15);
            ((_Float16*)Cout)[hidx] = (_Float16)gv;
          } else if constexpr (MODE == 2){
            float gv = int_gelu_f(h);
            float qf = fminf(fmaxf(rintf(gv / qs) + qzp, 0.0f), 255.0f);
            size_t bidx = ((((size_t)(m >> 5)) * (N >> 5) + (n >> 5)) << 10)
                        + ((size_t)((n >> 4) & 1) << 9) + ((m & 31) << 4) + (n & 15);
            ((int8_t*)Cout)[bidx] = (int8_t)((int)qf - 128);
          } else {
            ((float*)Cout)[(size_t)m * N + n] = h;
          }
        }
      }
    }
  }

  if constexpr (MODE == 0 || MODE == 3){
    __shared__ float redA[256], redB[256];
    redA[tid] = lmin; redB[tid] = lmax;
    __syncthreads();
    for (int st = 128; st > 0; st >>= 1){
      if (tid < st){
        redA[tid] = fminf(redA[tid], redA[tid + st]);
        redB[tid] = fmaxf(redB[tid], redB[tid + st]);
      }
      __syncthreads();
    }
    if (tid == 0){
      atomicMin(&sc[1], enc_f(redA[0]));
      atomicMax(&sc[5], enc_f(redB[0]));
    }
  }
}

extern "C" void kernel_launch(void* const* d_in, const int* in_sizes, int n_in,
                              void* d_out, int out_size, void* d_ws, size_t ws_size,
                              hipStream_t stream)
{
  const float* x  = (const float*)d_in[0];
  const float* w1 = (const float*)d_in[1];
  const float* b1 = (const float*)d_in[2];
  const float* w2 = (const float*)d_in[3];
  const float* b2 = (const float*)d_in[4];
  float* out = (float*)d_out;

  const int H = in_sizes[2];            // 3072
  const int D = in_sizes[4];            // 768
  const int M = in_sizes[0] / D;        // 12608 (multiple of 32)

  char* ws = (char*)d_ws;
  unsigned* sc = (unsigned*)ws;
  size_t off = 256;
  int8_t* qx  = (int8_t*)(ws + off); off += (size_t)M * D;   // 9.68 MB  (fragmented)
  int8_t* qw1 = (int8_t*)(ws + off); off += (size_t)H * D;   // 2.36 MB  (fragmented)
  int8_t* qw2 = (int8_t*)(ws + off); off += (size_t)D * H;   // 2.36 MB  (fragmented)
  int* rs1 = (int*)(ws + off); off += (size_t)H * 4;
  int* rs2 = (int*)(ws + off); off += 4096;
  int8_t* qg  = (int8_t*)(ws + off); off += (size_t)M * H;   // 38.7 MB  (fragmented)
  _Float16* g16 = (_Float16*)(ws + off);                      // 77.5 MB  (fragmented fp16)
  const size_t need_big = off + (size_t)M * H * 2;
  (void)n_in; (void)out_size;

  // scalar init: slots 0,1 = 0xFFFFFFFF (encoded +inf for min); 2..5 = 0
  hipMemsetAsync(sc, 0xFF, 8, stream);
  hipMemsetAsync(sc + 2, 0x00, 16, stream);

  reduce_stats<<<dim3(1280), dim3(256), 0, stream>>>(
      (const float4*)x, M * D / 4,
      (const float4*)w1, H * D / 4,
      (const float4*)w2, D * H / 4, sc);

  quant_all<<<dim3(2048 + H + D), dim3(256), 0, stream>>>(
      x, qx, (long)M * D / 16,
      w1, w2, qw1, qw2, rs1, rs2, sc, H, D);

  const dim3 g1(H / 128, (M + 127) / 128), g2(D / 128, (M + 127) / 128), blk(256);

  if (ws_size >= need_big){
    // GEMM1 (single pass): g stats + store g fp16 (fragmented)
    gemm_i8f<3><<<g1, blk, 0, stream>>>(qx, qw1, rs1, b1, g16, M, H, D, sc);
    // recode g (frag fp16) -> qg (frag int8)
    quant_g<<<dim3(2048), dim3(256), 0, stream>>>(
        (const vh8*)g16, (uint4*)qg, (long)M * H / 16, sc);
  } else {
    // fallback: exact 2-pass GEMM1 (stats, then quantize)
    gemm_i8f<0><<<g1, blk, 0, stream>>>(qx, qw1, rs1, b1, nullptr, M, H, D, sc);
    gemm_i8f<2><<<g1, blk, 0, stream>>>(qx, qw1, rs1, b1, qg, M, H, D, sc);
  }

  // GEMM2: out = qg @ qw2^T + b2
  gemm_i8f<1><<<g2, blk, 0, stream>>>(qg, qw2, rs2, b2, out, M, D, H, sc);
}